// Round 8
// baseline (168.179 us; speedup 1.0000x reference)
//
#include <hip/hip_runtime.h>

#define H 4096
#define W 4096
#define TH 4               // output rows per tile
#define NR (TH + 2)        // staged rows per tile (vertical halo)
#define BX 256             // threads per block
#define GX 4               // 4096 cols / (256 thr * 4 cols)
#define GY (H / TH)        // 1024 tile-rows
#define NTILE (GX * GY)    // 4096 tiles
#define TPB 4              // tiles per block (vertically adjacent)
#define NEDGE (NTILE / TPB)   // 1024 edge blocks
#define NKPB 16               // keypoint blocks (64 kp each)

#define MASK_W 1.0f
#define KPT_W 0.5f

struct Prep { float dx0, dx1, dx2, dx3, s0, s1, s2, s3; };
struct TileBuf { float4 pv[NR], tv[NR]; float hp[NR], ht[NR]; };

__device__ __forceinline__ float fast_sqrt(float x) {
    return __builtin_amdgcn_sqrtf(x);   // raw v_sqrt_f32 (~1 ulp)
}

// Issue all 12 float4 loads (+ edge-lane halo scalars) for one tile.
// No cross-lane ops here — shuffles happen at consume time.
__device__ __forceinline__ void load_tile(TileBuf& b,
                                          const float* __restrict__ bp,
                                          const float* __restrict__ bt,
                                          int r0, bool haloCol, bool isL) {
    #pragma unroll
    for (int r = 0; r < NR; ++r) {
        int row = r0 - 1 + r;
        bool valid = (unsigned)row < (unsigned)H;
        const float* pp = bp + (ptrdiff_t)row * W;
        const float* tt = bt + (ptrdiff_t)row * W;
        b.pv[r] = valid ? *(const float4*)pp : make_float4(0.f, 0.f, 0.f, 0.f);
        b.tv[r] = valid ? *(const float4*)tt : make_float4(0.f, 0.f, 0.f, 0.f);
        float h1 = 0.f, h2 = 0.f;
        if (valid & haloCol) {
            const float* q1 = isL ? pp - 1 : pp + 4;
            const float* q2 = isL ? tt - 1 : tt + 4;
            h1 = *q1; h2 = *q2;
        }
        b.hp[r] = h1; b.ht[r] = h2;
    }
}

// Cross-lane halo resolution + horizontal Sobel prep (consume time).
__device__ __forceinline__ Prep fin(float4 v, float h, bool isL, bool isR) {
    float lf = __shfl_up(v.w, 1);    // lane l <- lane l-1 .w == img[c-1]
    float rf = __shfl_down(v.x, 1);  // lane l <- lane l+1 .x == img[c+4]
    lf = isL ? h : lf;
    rf = isR ? h : rf;
    Prep o;
    o.dx0 = v.y - lf;
    o.dx1 = v.z - v.x;
    o.dx2 = v.w - v.y;
    o.dx3 = rf  - v.z;
    o.s0 = __fmaf_rn(2.f, v.x, lf  + v.y);
    o.s1 = __fmaf_rn(2.f, v.y, v.x + v.z);
    o.s2 = __fmaf_rn(2.f, v.z, v.y + v.w);
    o.s3 = __fmaf_rn(2.f, v.w, v.z + rf);
    return o;
}

__device__ __forceinline__ float edge1(float dxA, float dxB, float dxC, float sA, float sC) {
    float ex = dxA + __fmaf_rn(2.f, dxB, dxC);
    float ey = sC - sA;
    return fast_sqrt(__fmaf_rn(ex, ex, ey * ey));
}

__device__ __forceinline__ float compute_tile(const TileBuf& b, bool isL, bool isR, float acc) {
    Prep pA = fin(b.pv[0], b.hp[0], isL, isR);
    Prep tA = fin(b.tv[0], b.ht[0], isL, isR);
    Prep pB = fin(b.pv[1], b.hp[1], isL, isR);
    Prep tB = fin(b.tv[1], b.ht[1], isL, isR);
    #pragma unroll
    for (int i = 0; i < TH; ++i) {
        Prep pC = fin(b.pv[i + 2], b.hp[i + 2], isL, isR);
        Prep tC = fin(b.tv[i + 2], b.ht[i + 2], isL, isR);
        float pe, te, d;
        pe = edge1(pA.dx0, pB.dx0, pC.dx0, pA.s0, pC.s0);
        te = edge1(tA.dx0, tB.dx0, tC.dx0, tA.s0, tC.s0);
        d = pe - te; acc = __fmaf_rn(d, d, acc);
        pe = edge1(pA.dx1, pB.dx1, pC.dx1, pA.s1, pC.s1);
        te = edge1(tA.dx1, tB.dx1, tC.dx1, tA.s1, tC.s1);
        d = pe - te; acc = __fmaf_rn(d, d, acc);
        pe = edge1(pA.dx2, pB.dx2, pC.dx2, pA.s2, pC.s2);
        te = edge1(tA.dx2, tB.dx2, tC.dx2, tA.s2, tC.s2);
        d = pe - te; acc = __fmaf_rn(d, d, acc);
        pe = edge1(pA.dx3, pB.dx3, pC.dx3, pA.s3, pC.s3);
        te = edge1(tA.dx3, tB.dx3, tC.dx3, tA.s3, tC.s3);
        d = pe - te; acc = __fmaf_rn(d, d, acc);
        pA = pB; pB = pC;
        tA = tB; tB = tC;
    }
    return acc;
}

__global__ __launch_bounds__(BX) void fused_kernel(const float* __restrict__ pred,
                                                   const float* __restrict__ targ,
                                                   const float* __restrict__ kp,
                                                   float* __restrict__ ws) {
    int bid = blockIdx.x;

    if (bid < NEDGE) {
        // ============ edge loss: 4 vertically-adjacent tiles, 2-deep pipeline ============
        int gx = bid & (GX - 1);
        int gyb = (bid >> 2) * TPB;            // first tile-row of this block
        int c  = gx * (BX * 4) + threadIdx.x * 4;
        int lane = threadIdx.x & 63;
        bool isL = (lane == 0), isR = (lane == 63);
        bool haloCol = (isL & (c > 0)) | (isR & (c + 4 < W));

        const float* bp = pred + c;
        const float* bt = targ + c;

        TileBuf A, B;
        float acc = 0.f;

        load_tile(A, bp, bt, (gyb + 0) * TH, haloCol, isL);
        load_tile(B, bp, bt, (gyb + 1) * TH, haloCol, isL);
        acc = compute_tile(A, isL, isR, acc);
        load_tile(A, bp, bt, (gyb + 2) * TH, haloCol, isL);
        acc = compute_tile(B, isL, isR, acc);
        load_tile(B, bp, bt, (gyb + 3) * TH, haloCol, isL);
        acc = compute_tile(A, isL, isR, acc);
        acc = compute_tile(B, isL, isR, acc);

        // wave reduce (width 64)
        #pragma unroll
        for (int m = 32; m; m >>= 1) acc += __shfl_xor(acc, m);

        __shared__ float wsum[BX / 64];
        if ((threadIdx.x & 63) == 0) wsum[threadIdx.x >> 6] = acc;
        __syncthreads();
        if (threadIdx.x == 0) {
            float s = 0.f;
            #pragma unroll
            for (int i = 0; i < BX / 64; ++i) s += wsum[i];
            ws[bid] = s;
        }
    } else {
        // ======================= keypoint block =======================
        int t = threadIdx.x;
        if (t >= 64) return;
        int k = (bid - NEDGE) * 64 + t;        // keypoint index 0..1023

        float gx = kp[2 * k];
        float gy = kp[2 * k + 1];
        float x = (gx + 1.f) * (W * 0.5f) - 0.5f;
        float y = (gy + 1.f) * (H * 0.5f) - 0.5f;
        float fx0 = floorf(x), fy0 = floorf(y);
        int x0 = (int)fx0, y0 = (int)fy0;
        int x1 = x0 + 1, y1 = y0 + 1;
        float wx1 = x - fx0, wx0 = 1.f - wx1;
        float wy1 = y - fy0, wy0 = 1.f - wy1;

        // 6x6 pred_seg patch around (y0, x0), zero-padded
        float sg[6][6];
        #pragma unroll
        for (int i = 0; i < 6; ++i) {
            int rr = y0 - 2 + i;
            #pragma unroll
            for (int j = 0; j < 6; ++j) {
                int cc = x0 - 2 + j;
                bool ok = (rr >= 0) & (rr < H) & (cc >= 0) & (cc < W);
                sg[i][j] = ok ? pred[(size_t)rr * W + cc] : 0.f;
            }
        }

        // 4x4 pred_edge for rows y0-1..y0+2, cols x0-1..x0+2 (0 when OOB)
        float e[4][4];
        #pragma unroll
        for (int i = 0; i < 4; ++i) {
            int rr = y0 - 1 + i;
            #pragma unroll
            for (int j = 0; j < 4; ++j) {
                int cc = x0 - 1 + j;
                if (rr < 0 || rr >= H || cc < 0 || cc >= W) { e[i][j] = 0.f; continue; }
                float ex = (sg[i][j + 2] - sg[i][j])
                         + 2.f * (sg[i + 1][j + 2] - sg[i + 1][j])
                         + (sg[i + 2][j + 2] - sg[i + 2][j]);
                float ey = (sg[i + 2][j] + 2.f * sg[i + 2][j + 1] + sg[i + 2][j + 2])
                         - (sg[i][j] + 2.f * sg[i][j + 1] + sg[i][j + 2]);
                e[i][j] = fast_sqrt(__fmaf_rn(ex, ex, ey * ey));
            }
        }

        // 2x2 distance-map values (3x3 box over pred_edge)
        float dmap[2][2];
        #pragma unroll
        for (int a = 0; a < 2; ++a) {
            #pragma unroll
            for (int b = 0; b < 2; ++b) {
                float s = 0.f;
                #pragma unroll
                for (int i = 0; i < 3; ++i)
                    #pragma unroll
                    for (int j = 0; j < 3; ++j) s += e[a + i][b + j];
                dmap[a][b] = s;
            }
        }

        bool vx0 = (x0 >= 0) & (x0 < W), vx1 = (x1 >= 0) & (x1 < W);
        bool vy0 = (y0 >= 0) & (y0 < H), vy1 = (y1 >= 0) & (y1 < H);
        float v00 = (vx0 & vy0) ? dmap[0][0] : 0.f;
        float v01 = (vx1 & vy0) ? dmap[0][1] : 0.f;
        float v10 = (vx0 & vy1) ? dmap[1][0] : 0.f;
        float v11 = (vx1 & vy1) ? dmap[1][1] : 0.f;
        float kd = wx0 * wy0 * v00 + wx1 * wy0 * v01
                 + wx0 * wy1 * v10 + wx1 * wy1 * v11;

        // wave reduce 64 kd values
        #pragma unroll
        for (int m = 32; m; m >>= 1) kd += __shfl_xor(kd, m);
        if (t == 0) ws[NEDGE + (bid - NEDGE)] = kd;
    }
}

__global__ __launch_bounds__(256) void final_kernel(const float* __restrict__ ws,
                                                    float* __restrict__ out) {
    int t = threadIdx.x;
    float es = 0.f;
    #pragma unroll
    for (int i = 0; i < NEDGE / 256; ++i) es += ws[t + i * 256];
    float ks = (t < NKPB) ? ws[NEDGE + t] : 0.f;

    #pragma unroll
    for (int m = 32; m; m >>= 1) {
        es += __shfl_xor(es, m);
        ks += __shfl_xor(ks, m);
    }
    __shared__ float res[4], rks[4];
    int wid = t >> 6;
    if ((t & 63) == 0) { res[wid] = es; rks[wid] = ks; }
    __syncthreads();
    if (t == 0) {
        float e2 = res[0] + res[1] + res[2] + res[3];
        float k2 = rks[0] + rks[1] + rks[2] + rks[3];
        float edge_loss = e2 * (1.f / ((float)H * (float)W));
        float constraint_loss = k2 * (1.f / 1024.f);
        out[0] = MASK_W * edge_loss + KPT_W * constraint_loss;
    }
}

extern "C" void kernel_launch(void* const* d_in, const int* in_sizes, int n_in,
                              void* d_out, int out_size, void* d_ws, size_t ws_size,
                              hipStream_t stream) {
    const float* kp   = (const float*)d_in[0];
    const float* pred = (const float*)d_in[2];
    const float* targ = (const float*)d_in[3];
    float* out = (float*)d_out;
    float* ws  = (float*)d_ws;

    fused_kernel<<<NEDGE + NKPB, BX, 0, stream>>>(pred, targ, kp, ws);
    final_kernel<<<1, 256, 0, stream>>>(ws, out);
}